// Round 1
// baseline (239.119 us; speedup 1.0000x reference)
//
#include <hip/hip_runtime.h>

// ---------------------------------------------------------------------------
// FactorizedSynthesizerRandom: B=8, S=2048, D=1024, K=8
//   q = x@Wq+bq, k = x@Wk+bk  (rank-8)
//   attn = softmax(q k^T)                        -> output[1] (f32, 8x2048x2048)
//   out  = attn @ (x@Wv+bv)                      -> output[0] (f32, 8x2048x1024)
// Strategy: bf16 MFMA (16x16x32) for the two big GEMMs, f32 accum.
// ---------------------------------------------------------------------------

typedef __attribute__((ext_vector_type(8))) __bf16 bf16x8;
typedef __attribute__((ext_vector_type(4))) __bf16 bf16x4;
typedef __attribute__((ext_vector_type(4))) float  f32x4;
typedef unsigned int u32;

#define GLB_CAST(p) ((const __attribute__((address_space(1))) u32*)(p))
#define LDS_CAST(p) ((__attribute__((address_space(3))) u32*)(p))

static constexpr int    Bn   = 8;
static constexpr int    S    = 2048;
static constexpr int    Dd   = 1024;
static constexpr int    Mtot = Bn * S;            // 16384
static constexpr size_t OUT0 = (size_t)Bn * S * Dd;   // 16777216 floats (out)

// workspace layout (bytes)
static constexpr size_t OFF_XBF  = 0;                          // [16384][1024] bf16
static constexpr size_t OFF_WVT  = OFF_XBF  + (size_t)Mtot * Dd * 2;   // [1024][1024] bf16 (Wv^T)
static constexpr size_t OFF_WQKT = OFF_WVT  + (size_t)Dd * Dd * 2;     // [16][1024] bf16
static constexpr size_t OFF_Q    = OFF_WQKT + (size_t)16 * Dd * 2;     // [16384][8] f32
static constexpr size_t OFF_K    = OFF_Q    + (size_t)Mtot * 8 * 4;    // [16384][8] f32
static constexpr size_t OFF_VT   = OFF_K    + (size_t)Mtot * 8 * 4;    // [8][1024][2048] bf16 (value^T)
static constexpr size_t OFF_ATTB = OFF_VT   + (size_t)Bn * Dd * S * 2; // [8][2048][2048] bf16
static constexpr size_t WS_NEED  = OFF_ATTB + (size_t)Bn * S * S * 2;  // ~137 MB

// ---------------------------------------------------------------------------
// prep: blocks [0,4096): x f32 -> bf16 ; [4096,4352): Wv -> Wv^T bf16 ;
//       [4352,4368): [Wq|Wk]^T bf16  ([16][1024])
// ---------------------------------------------------------------------------
__global__ __launch_bounds__(256) void prep_kernel(
    const float* __restrict__ x, const float* __restrict__ Wq,
    const float* __restrict__ Wk, const float* __restrict__ Wv,
    __bf16* __restrict__ xbf, __bf16* __restrict__ wvt, __bf16* __restrict__ wqkT)
{
    __shared__ float lt[64][65];
    int bid = blockIdx.x, t = threadIdx.x;
    if (bid < 4096) {
        #pragma unroll
        for (int i = 0; i < 4; ++i) {
            size_t idx4 = (size_t)i * 1048576 + (size_t)bid * 256 + t;  // float4 index
            f32x4 v = ((const f32x4*)x)[idx4];
            bf16x4 o;
            #pragma unroll
            for (int c = 0; c < 4; ++c) o[c] = (__bf16)v[c];
            ((bf16x4*)xbf)[idx4] = o;
        }
    } else if (bid < 4352) {
        int tile = bid - 4096;             // 256 tiles of 64x64
        int tr = tile >> 4, tc = tile & 15;
        int r0 = t >> 6, c = t & 63;
        #pragma unroll
        for (int i = 0; i < 16; ++i) {
            int row = i * 4 + r0;
            lt[row][c] = Wv[(size_t)(tr * 64 + row) * 1024 + tc * 64 + c];
        }
        __syncthreads();
        #pragma unroll
        for (int i = 0; i < 16; ++i) {
            int er = i * 4 + r0;
            wvt[(size_t)(tc * 64 + er) * 1024 + tr * 64 + c] = (__bf16)lt[c][er];
        }
    } else {
        int lb = bid - 4352;               // 16 blocks cover 16*1024 elems
        #pragma unroll
        for (int i = 0; i < 4; ++i) {
            int idx = (lb * 4 + i) * 256 + t;   // 0..16383
            int n = idx >> 10, d = idx & 1023;
            float v = (n < 8) ? Wq[d * 8 + n] : Wk[d * 8 + (n & 7)];
            wqkT[n * 1024 + d] = (__bf16)v;
        }
    }
}

// ---------------------------------------------------------------------------
// q/k projection: one wave per 16 rows; C-tile is a single 16x16 fragment.
// Cols 0-7 -> q, 8-15 -> k.  C/D layout: col=lane&15, row=4*(lane>>4)+reg.
// ---------------------------------------------------------------------------
__global__ __launch_bounds__(256) void qk_proj_kernel(
    const __bf16* __restrict__ xbf, const __bf16* __restrict__ wqkT,
    const float* __restrict__ bq, const float* __restrict__ bk,
    float* __restrict__ qb, float* __restrict__ kb)
{
    int t = threadIdx.x, l = t & 63, w = t >> 6;
    int mbase = (blockIdx.x * 4 + w) * 16;
    f32x4 acc = {0.f, 0.f, 0.f, 0.f};
    const __bf16* ar = xbf + (size_t)(mbase + (l & 15)) * 1024 + ((l >> 4) << 3);
    const __bf16* br = wqkT + (size_t)(l & 15) * 1024 + ((l >> 4) << 3);
    #pragma unroll 8
    for (int kk = 0; kk < 1024; kk += 32) {
        bf16x8 a = *(const bf16x8*)(ar + kk);
        bf16x8 b = *(const bf16x8*)(br + kk);
        acc = __builtin_amdgcn_mfma_f32_16x16x32_bf16(a, b, acc, 0, 0, 0);
    }
    int n = l & 15;
    float bias = (n < 8) ? bq[n] : bk[n & 7];
    #pragma unroll
    for (int r = 0; r < 4; ++r) {
        int m = mbase + ((l >> 4) << 2) + r;
        float v = acc[r] + bias;
        if (n < 8) qb[m * 8 + n] = v;
        else       kb[m * 8 + (n & 7)] = v;
    }
}

// ---------------------------------------------------------------------------
// softmax: block=256 threads; thread t owns cols j = t*8..t*8+7, keeps the
// k-slice (8x8 f32) in registers for all 32 rows of its chunk.
// Writes attn f32 (d_out) and attn bf16 (ws, for PV GEMM).
// ---------------------------------------------------------------------------
__global__ __launch_bounds__(256) void softmax_kernel(
    const float* __restrict__ qb, const float* __restrict__ kb,
    float* __restrict__ attnF, __bf16* __restrict__ attnB)
{
    int bid = blockIdx.x;
    int b = bid >> 6, chunk = bid & 63;       // 64 chunks x 32 rows = 2048
    int t = threadIdx.x, l = t & 63, w = t >> 6;
    float kr[8][8];
    const float* kbb = kb + ((size_t)b << 14);
    #pragma unroll
    for (int jj = 0; jj < 8; ++jj) {
        f32x4 v0 = *(const f32x4*)(kbb + (size_t)(t * 8 + jj) * 8);
        f32x4 v1 = *(const f32x4*)(kbb + (size_t)(t * 8 + jj) * 8 + 4);
        #pragma unroll
        for (int c = 0; c < 4; ++c) { kr[jj][c] = v0[c]; kr[jj][4 + c] = v1[c]; }
    }
    __shared__ float redm[4], reds[4];
    const float* qrow = qb + ((size_t)b << 14);
    for (int ii = 0; ii < 32; ++ii) {
        int i = (chunk << 5) + ii;
        f32x4 q0 = *(const f32x4*)(qrow + (size_t)i * 8);
        f32x4 q1 = *(const f32x4*)(qrow + (size_t)i * 8 + 4);
        float e[8];
        #pragma unroll
        for (int jj = 0; jj < 8; ++jj) {
            float s = q0[0] * kr[jj][0];
            s = fmaf(q0[1], kr[jj][1], s);
            s = fmaf(q0[2], kr[jj][2], s);
            s = fmaf(q0[3], kr[jj][3], s);
            s = fmaf(q1[0], kr[jj][4], s);
            s = fmaf(q1[1], kr[jj][5], s);
            s = fmaf(q1[2], kr[jj][6], s);
            s = fmaf(q1[3], kr[jj][7], s);
            e[jj] = s;
        }
        float mx = e[0];
        #pragma unroll
        for (int jj = 1; jj < 8; ++jj) mx = fmaxf(mx, e[jj]);
        #pragma unroll
        for (int d = 1; d < 64; d <<= 1) mx = fmaxf(mx, __shfl_xor(mx, d));
        if (l == 0) redm[w] = mx;
        __syncthreads();
        mx = fmaxf(fmaxf(redm[0], redm[1]), fmaxf(redm[2], redm[3]));
        float p[8], sum = 0.f;
        #pragma unroll
        for (int jj = 0; jj < 8; ++jj) { p[jj] = __expf(e[jj] - mx); sum += p[jj]; }
        #pragma unroll
        for (int d = 1; d < 64; d <<= 1) sum += __shfl_xor(sum, d);
        if (l == 0) reds[w] = sum;
        __syncthreads();
        float T = (reds[0] + reds[1]) + (reds[2] + reds[3]);
        float inv = 1.0f / T;
        size_t off = (((size_t)b << 11) + i) * 2048 + (size_t)t * 8;
        f32x4 o0, o1; bf16x8 ob;
        #pragma unroll
        for (int c = 0; c < 4; ++c) {
            o0[c] = p[c] * inv; o1[c] = p[4 + c] * inv;
            ob[c] = (__bf16)o0[c]; ob[4 + c] = (__bf16)o1[c];
        }
        *(f32x4*)(attnF + off) = o0;
        *(f32x4*)(attnF + off + 4) = o1;
        *(bf16x8*)(attnB + off) = ob;
    }
}

// ---------------------------------------------------------------------------
// Shared GEMM: C[128x128 tile] = A[M][Kz] * Bt[N][Kz]^T, both bf16 row-major
// with row stride == Kz (lda==ldb in both uses). LDS tiles [128][64] bf16 with
// 16B-slot XOR swizzle (slot ^= row&7), staged via global_load_lds dwordx4
// with pre-swizzled global source. 4 waves, 64x64 per wave, 16x16x32 MFMA.
// MODE 0: out = value^T bf16 ([b][e][s]) with bias bv[e]   (A=xbf, Bt=WvT)
// MODE 1: out = f32 [b][i][e]                              (A=attnB, Bt=valueT)
// ---------------------------------------------------------------------------
template<int MODE>
__global__ __launch_bounds__(256) void gemm_kernel(
    const __bf16* __restrict__ A, const __bf16* __restrict__ Bt,
    float* __restrict__ outF, __bf16* __restrict__ outVt,
    const float* __restrict__ bv, int Ksz)
{
    __shared__ __bf16 As[128 * 64];
    __shared__ __bf16 Bs[128 * 64];
    int bid = blockIdx.x;
    int wg = ((bid & 7) << 7) | (bid >> 3);    // XCD-contiguous swizzle (nwg=1024)
    int t = threadIdx.x, l = t & 63, w = t >> 6;

    int mblk, nblk, bb = 0;
    size_t aoff, boff;
    if constexpr (MODE == 0) {
        mblk = wg >> 3; nblk = wg & 7;
        aoff = (size_t)mblk * 128 * 1024; boff = 0;
    } else {
        bb = wg >> 7; int r = wg & 127; mblk = r >> 3; nblk = r & 7;
        aoff = (size_t)bb * S * S + (size_t)mblk * 128 * 2048;
        boff = (size_t)bb * Dd * S;
    }
    const int lda = (MODE == 0) ? 1024 : 2048;
    const __bf16* Ab = A + aoff;
    const __bf16* Bb = Bt + boff + (size_t)nblk * 128 * lda;

    int rowin = l >> 3, pslot = l & 7;
    int sl = pslot ^ rowin;                   // pre-swizzled source slot
    int wr = (w >> 1) << 6, wc = (w & 1) << 6;
    f32x4 acc[4][4] = {};

    for (int kk = 0; kk < Ksz; kk += 64) {
        #pragma unroll
        for (int c = 0; c < 4; ++c) {
            int g = c * 4 + w;                // 16 groups of 8 rows
            const __bf16* ga = Ab + (size_t)(g * 8 + rowin) * lda + kk + sl * 8;
            __builtin_amdgcn_global_load_lds(GLB_CAST(ga), LDS_CAST(&As[g * 512]), 16, 0, 0);
            const __bf16* gb = Bb + (size_t)(g * 8 + rowin) * lda + kk + sl * 8;
            __builtin_amdgcn_global_load_lds(GLB_CAST(gb), LDS_CAST(&Bs[g * 512]), 16, 0, 0);
        }
        __syncthreads();
        bf16x8 af[2][4], bfr[2][4];
        #pragma unroll
        for (int ks = 0; ks < 2; ++ks) {
            int sa = ks * 4 + (l >> 4);
            #pragma unroll
            for (int i = 0; i < 4; ++i) {
                int ra = wr + i * 16 + (l & 15);
                af[ks][i] = *(const bf16x8*)&As[ra * 64 + ((sa ^ (ra & 7)) << 3)];
                int rb = wc + i * 16 + (l & 15);
                bfr[ks][i] = *(const bf16x8*)&Bs[rb * 64 + ((sa ^ (rb & 7)) << 3)];
            }
        }
        #pragma unroll
        for (int i = 0; i < 4; ++i)
            #pragma unroll
            for (int j = 0; j < 4; ++j) {
                acc[i][j] = __builtin_amdgcn_mfma_f32_16x16x32_bf16(af[0][i], bfr[0][j], acc[i][j], 0, 0, 0);
                acc[i][j] = __builtin_amdgcn_mfma_f32_16x16x32_bf16(af[1][i], bfr[1][j], acc[i][j], 0, 0, 0);
            }
        __syncthreads();
    }

    if constexpr (MODE == 0) {
        #pragma unroll
        for (int j = 0; j < 4; ++j) {
            int e = (nblk << 7) + wc + j * 16 + (l & 15);
            float bias = bv[e];
            #pragma unroll
            for (int i = 0; i < 4; ++i) {
                int m0 = (mblk << 7) + wr + i * 16 + ((l >> 4) << 2);
                int b = m0 >> 11, s0 = m0 & 2047;
                bf16x4 o;
                #pragma unroll
                for (int r = 0; r < 4; ++r) o[r] = (__bf16)(acc[i][j][r] + bias);
                *(bf16x4*)&outVt[(((size_t)(b << 10) + e) << 11) + s0] = o;
            }
        }
    } else {
        float* ob = outF + (size_t)bb * S * Dd;
        #pragma unroll
        for (int i = 0; i < 4; ++i) {
            int m0 = (mblk << 7) + wr + i * 16 + ((l >> 4) << 2);
            #pragma unroll
            for (int j = 0; j < 4; ++j) {
                int e = (nblk << 7) + wc + j * 16 + (l & 15);
                #pragma unroll
                for (int r = 0; r < 4; ++r)
                    ob[(size_t)(m0 + r) * 1024 + e] = acc[i][j][r];
            }
        }
    }
}

// ---------------------------------------------------------------------------
extern "C" void kernel_launch(void* const* d_in, const int* in_sizes, int n_in,
                              void* d_out, int out_size, void* d_ws, size_t ws_size,
                              hipStream_t stream)
{
    const float* x  = (const float*)d_in[0];
    const float* Wq = (const float*)d_in[1];
    const float* bq = (const float*)d_in[2];
    const float* Wk = (const float*)d_in[3];
    const float* bk = (const float*)d_in[4];
    const float* Wv = (const float*)d_in[5];
    const float* bv = (const float*)d_in[6];

    float* outp  = (float*)d_out;
    float* attnF = outp + OUT0;

    if (ws_size < WS_NEED) return;  // clean failure instead of corruption
    char* ws = (char*)d_ws;
    __bf16* xbf   = (__bf16*)(ws + OFF_XBF);
    __bf16* wvt   = (__bf16*)(ws + OFF_WVT);
    __bf16* wqkT  = (__bf16*)(ws + OFF_WQKT);
    float*  qbuf  = (float*)(ws + OFF_Q);
    float*  kbuf  = (float*)(ws + OFF_K);
    __bf16* vt    = (__bf16*)(ws + OFF_VT);
    __bf16* attnB = (__bf16*)(ws + OFF_ATTB);

    prep_kernel<<<4368, 256, 0, stream>>>(x, Wq, Wk, Wv, xbf, wvt, wqkT);
    qk_proj_kernel<<<256, 256, 0, stream>>>(xbf, wqkT, bq, bk, qbuf, kbuf);
    gemm_kernel<0><<<1024, 256, 0, stream>>>(xbf, wvt, nullptr, vt, bv, 1024);
    softmax_kernel<<<512, 256, 0, stream>>>(qbuf, kbuf, attnF, attnB);
    gemm_kernel<1><<<1024, 256, 0, stream>>>(attnB, vt, outp, nullptr, nullptr, 2048);
}

// Round 2
// 197.991 us; speedup vs baseline: 1.2077x; 1.2077x over previous
//
#include <hip/hip_runtime.h>

// ---------------------------------------------------------------------------
// FactorizedSynthesizerRandom: B=8, S=2048, D=1024, K=8
//   q = x@Wq+bq, k = x@Wk+bk  (rank-8)
//   attn = softmax(q k^T)                        -> output[1] (f32, 8x2048x2048)
//   out  = attn @ (x@Wv+bv)                      -> output[0] (f32, 8x2048x1024)
// Round 2: 256x256-tile BK=64 deep-pipelined GEMM (counted vmcnt, raw barriers,
//          setprio, XOR-swizzled LDS), 8 waves / 512 threads, 128 KiB LDS.
// ---------------------------------------------------------------------------

typedef __attribute__((ext_vector_type(8))) __bf16 bf16x8;
typedef __attribute__((ext_vector_type(4))) __bf16 bf16x4;
typedef __attribute__((ext_vector_type(4))) float  f32x4;
typedef unsigned int u32;

#define GLB_CAST(p) ((const __attribute__((address_space(1))) u32*)(p))
#define LDS_CAST(p) ((__attribute__((address_space(3))) u32*)(p))

#define S_BARRIER() { __builtin_amdgcn_s_barrier(); __builtin_amdgcn_sched_barrier(0); }
#define VMCNT8()    { asm volatile("s_waitcnt vmcnt(8)" ::: "memory"); __builtin_amdgcn_sched_barrier(0); }
#define VMCNT0()    { asm volatile("s_waitcnt vmcnt(0)" ::: "memory"); __builtin_amdgcn_sched_barrier(0); }

static constexpr int    Bn   = 8;
static constexpr int    S    = 2048;
static constexpr int    Dd   = 1024;
static constexpr int    Mtot = Bn * S;            // 16384
static constexpr size_t OUT0 = (size_t)Bn * S * Dd;   // out elements

// workspace layout (bytes)
static constexpr size_t OFF_XBF  = 0;                          // [16384][1024] bf16
static constexpr size_t OFF_WVT  = OFF_XBF  + (size_t)Mtot * Dd * 2;   // [1024][1024] bf16 (Wv^T)
static constexpr size_t OFF_WQKT = OFF_WVT  + (size_t)Dd * Dd * 2;     // [16][1024] bf16
static constexpr size_t OFF_Q    = OFF_WQKT + (size_t)16 * Dd * 2;     // [16384][8] f32
static constexpr size_t OFF_K    = OFF_Q    + (size_t)Mtot * 8 * 4;    // [16384][8] f32
static constexpr size_t OFF_VT   = OFF_K    + (size_t)Mtot * 8 * 4;    // [8][1024][2048] bf16 (value^T)
static constexpr size_t OFF_ATTB = OFF_VT   + (size_t)Bn * Dd * S * 2; // [8][2048][2048] bf16
static constexpr size_t WS_NEED  = OFF_ATTB + (size_t)Bn * S * S * 2;  // ~137 MB

// ---------------------------------------------------------------------------
// prep: blocks [0,4096): x f32 -> bf16 ; [4096,4352): Wv -> Wv^T bf16 ;
//       [4352,4368): [Wq|Wk]^T bf16  ([16][1024])
// ---------------------------------------------------------------------------
__global__ __launch_bounds__(256) void prep_kernel(
    const float* __restrict__ x, const float* __restrict__ Wq,
    const float* __restrict__ Wk, const float* __restrict__ Wv,
    __bf16* __restrict__ xbf, __bf16* __restrict__ wvt, __bf16* __restrict__ wqkT)
{
    __shared__ float lt[64][65];
    int bid = blockIdx.x, t = threadIdx.x;
    if (bid < 4096) {
        #pragma unroll
        for (int i = 0; i < 4; ++i) {
            size_t idx4 = (size_t)i * 1048576 + (size_t)bid * 256 + t;  // float4 index
            f32x4 v = ((const f32x4*)x)[idx4];
            bf16x4 o;
            #pragma unroll
            for (int c = 0; c < 4; ++c) o[c] = (__bf16)v[c];
            ((bf16x4*)xbf)[idx4] = o;
        }
    } else if (bid < 4352) {
        int tile = bid - 4096;             // 256 tiles of 64x64
        int tr = tile >> 4, tc = tile & 15;
        int r0 = t >> 6, c = t & 63;
        #pragma unroll
        for (int i = 0; i < 16; ++i) {
            int row = i * 4 + r0;
            lt[row][c] = Wv[(size_t)(tr * 64 + row) * 1024 + tc * 64 + c];
        }
        __syncthreads();
        #pragma unroll
        for (int i = 0; i < 16; ++i) {
            int er = i * 4 + r0;
            wvt[(size_t)(tc * 64 + er) * 1024 + tr * 64 + c] = (__bf16)lt[c][er];
        }
    } else {
        int lb = bid - 4352;               // 16 blocks cover 16*1024 elems
        #pragma unroll
        for (int i = 0; i < 4; ++i) {
            int idx = (lb * 4 + i) * 256 + t;   // 0..16383
            int n = idx >> 10, d = idx & 1023;
            float v = (n < 8) ? Wq[d * 8 + n] : Wk[d * 8 + (n & 7)];
            wqkT[n * 1024 + d] = (__bf16)v;
        }
    }
}

// ---------------------------------------------------------------------------
// q/k projection (rank-8, tiny): one wave per 16 rows, single 16x16 fragment.
// ---------------------------------------------------------------------------
__global__ __launch_bounds__(256) void qk_proj_kernel(
    const __bf16* __restrict__ xbf, const __bf16* __restrict__ wqkT,
    const float* __restrict__ bq, const float* __restrict__ bk,
    float* __restrict__ qb, float* __restrict__ kb)
{
    int t = threadIdx.x, l = t & 63, w = t >> 6;
    int mbase = (blockIdx.x * 4 + w) * 16;
    f32x4 acc = {0.f, 0.f, 0.f, 0.f};
    const __bf16* ar = xbf + (size_t)(mbase + (l & 15)) * 1024 + ((l >> 4) << 3);
    const __bf16* br = wqkT + (size_t)(l & 15) * 1024 + ((l >> 4) << 3);
    #pragma unroll 8
    for (int kk = 0; kk < 1024; kk += 32) {
        bf16x8 a = *(const bf16x8*)(ar + kk);
        bf16x8 b = *(const bf16x8*)(br + kk);
        acc = __builtin_amdgcn_mfma_f32_16x16x32_bf16(a, b, acc, 0, 0, 0);
    }
    int n = l & 15;
    float bias = (n < 8) ? bq[n] : bk[n & 7];
    #pragma unroll
    for (int r = 0; r < 4; ++r) {
        int m = mbase + ((l >> 4) << 2) + r;
        float v = acc[r] + bias;
        if (n < 8) qb[m * 8 + n] = v;
        else       kb[m * 8 + (n & 7)] = v;
    }
}

// ---------------------------------------------------------------------------
// softmax: thread t owns cols j = t*8..t*8+7, k-slice in registers.
// Writes attn f32 (d_out) and attn bf16 (ws, PV GEMM input).
// ---------------------------------------------------------------------------
__global__ __launch_bounds__(256) void softmax_kernel(
    const float* __restrict__ qb, const float* __restrict__ kb,
    float* __restrict__ attnF, __bf16* __restrict__ attnB)
{
    int bid = blockIdx.x;
    int b = bid >> 6, chunk = bid & 63;       // 64 chunks x 32 rows = 2048
    int t = threadIdx.x, l = t & 63, w = t >> 6;
    float kr[8][8];
    const float* kbb = kb + ((size_t)b << 14);
    #pragma unroll
    for (int jj = 0; jj < 8; ++jj) {
        f32x4 v0 = *(const f32x4*)(kbb + (size_t)(t * 8 + jj) * 8);
        f32x4 v1 = *(const f32x4*)(kbb + (size_t)(t * 8 + jj) * 8 + 4);
        #pragma unroll
        for (int c = 0; c < 4; ++c) { kr[jj][c] = v0[c]; kr[jj][4 + c] = v1[c]; }
    }
    __shared__ float redm[4], reds[4];
    const float* qrow = qb + ((size_t)b << 14);
    for (int ii = 0; ii < 32; ++ii) {
        int i = (chunk << 5) + ii;
        f32x4 q0 = *(const f32x4*)(qrow + (size_t)i * 8);
        f32x4 q1 = *(const f32x4*)(qrow + (size_t)i * 8 + 4);
        float e[8];
        #pragma unroll
        for (int jj = 0; jj < 8; ++jj) {
            float s = q0[0] * kr[jj][0];
            s = fmaf(q0[1], kr[jj][1], s);
            s = fmaf(q0[2], kr[jj][2], s);
            s = fmaf(q0[3], kr[jj][3], s);
            s = fmaf(q1[0], kr[jj][4], s);
            s = fmaf(q1[1], kr[jj][5], s);
            s = fmaf(q1[2], kr[jj][6], s);
            s = fmaf(q1[3], kr[jj][7], s);
            e[jj] = s;
        }
        float mx = e[0];
        #pragma unroll
        for (int jj = 1; jj < 8; ++jj) mx = fmaxf(mx, e[jj]);
        #pragma unroll
        for (int d = 1; d < 64; d <<= 1) mx = fmaxf(mx, __shfl_xor(mx, d));
        if (l == 0) redm[w] = mx;
        __syncthreads();
        mx = fmaxf(fmaxf(redm[0], redm[1]), fmaxf(redm[2], redm[3]));
        float p[8], sum = 0.f;
        #pragma unroll
        for (int jj = 0; jj < 8; ++jj) { p[jj] = __expf(e[jj] - mx); sum += p[jj]; }
        #pragma unroll
        for (int d = 1; d < 64; d <<= 1) sum += __shfl_xor(sum, d);
        if (l == 0) reds[w] = sum;
        __syncthreads();
        float T = (reds[0] + reds[1]) + (reds[2] + reds[3]);
        float inv = 1.0f / T;
        size_t off = (((size_t)b << 11) + i) * 2048 + (size_t)t * 8;
        f32x4 o0, o1; bf16x8 ob;
        #pragma unroll
        for (int c = 0; c < 4; ++c) {
            o0[c] = p[c] * inv; o1[c] = p[4 + c] * inv;
            ob[c] = (__bf16)o0[c]; ob[4 + c] = (__bf16)o1[c];
        }
        *(f32x4*)(attnF + off) = o0;
        *(f32x4*)(attnF + off + 4) = o1;
        *(bf16x8*)(attnB + off) = ob;
    }
}

// ---------------------------------------------------------------------------
// Deep-pipelined GEMM: C[256x256] = A[M][Kz] * Bt[N][Kz]^T (bf16, row-major,
// row stride = Kz). 512 threads = 8 waves (2M x 4N), per-wave 128x64 output.
// LDS: 2 slots x (A 32KB + B 32KB) = 128 KiB, 16B-slot XOR swizzle
// (slot ^= row&7) via pre-swizzled global source. Pipeline: entering tile t,
// tile t+1's 8 loads are in flight; after frag-reads of t complete (raw
// barrier), stage t+2 into slot t&1, vmcnt(8) (never 0 mid-loop) + raw
// barrier publishes t+1.
// MODE 0: out = value^T bf16 [b][e][s] + bias bv[e]  (A=xbf M=16384, Bt=WvT N=1024, K=1024)
// MODE 1: out = f32 [b][i][e]                        (A=attnB M=2048/b, Bt=vt N=1024, K=2048)
// ---------------------------------------------------------------------------
template<int LDA>
__device__ __forceinline__ void stage_tile(const __bf16* Ab, const __bf16* Bb,
    char* smem, int slot, int kk, int rowin, int sl8, int wid)
{
    #pragma unroll
    for (int r = 0; r < 4; ++r) {
        __builtin_amdgcn_global_load_lds(
            GLB_CAST(Ab + (size_t)(r * 64 + rowin) * LDA + kk + sl8 * 8),
            LDS_CAST(smem + slot * 65536 + r * 8192 + wid * 1024), 16, 0, 0);
        __builtin_amdgcn_global_load_lds(
            GLB_CAST(Bb + (size_t)(r * 64 + rowin) * LDA + kk + sl8 * 8),
            LDS_CAST(smem + slot * 65536 + 32768 + r * 8192 + wid * 1024), 16, 0, 0);
    }
}

template<int MODE>
__global__ __launch_bounds__(512, 2) void gemm_kernel(
    const __bf16* __restrict__ A, const __bf16* __restrict__ Bt,
    float* __restrict__ outF, __bf16* __restrict__ outVt,
    const float* __restrict__ bv)
{
    constexpr int LDA = (MODE == 0) ? 1024 : 2048;
    constexpr int NT  = LDA / 64;               // K-tiles (K == LDA in both uses)
    __shared__ __align__(1024) char smem[131072];

    int bid = blockIdx.x;
    int wg = ((bid & 7) << 5) | (bid >> 3);     // bijective XCD swizzle (nwg=256)
    int t = threadIdx.x, l = t & 63;
    int wid = t >> 6;
    int wmr = wid >> 2, wnc = wid & 3;          // wave grid 2(M) x 4(N)

    int mblk, nblk, bb = 0;
    size_t aoff, boff;
    if constexpr (MODE == 0) {
        mblk = wg >> 2; nblk = wg & 3;          // 64 x 4
        aoff = (size_t)mblk * 256 * LDA; boff = 0;
    } else {
        bb = wg >> 5; int r = wg & 31;          // one batch per XCD
        mblk = r >> 2; nblk = r & 3;            // 8 x 4
        aoff = (size_t)bb * S * S + (size_t)mblk * 256 * LDA;
        boff = (size_t)bb * Dd * S;
    }
    const __bf16* Ab = A + aoff;
    const __bf16* Bb = Bt + boff + (size_t)nblk * 256 * LDA;

    int rowin = t >> 3;                         // 0..63
    int sl8 = (t & 7) ^ (rowin & 7);            // pre-swizzled global 16B-slot
    int lr = l & 15, lk = l >> 4;

    f32x4 acc[8][4] = {};

    // prologue: tiles 0,1 in flight; wait tile0, publish.
    stage_tile<LDA>(Ab, Bb, smem, 0, 0, rowin, sl8, wid);
    stage_tile<LDA>(Ab, Bb, smem, 1, 64, rowin, sl8, wid);
    VMCNT8();
    S_BARRIER();

    for (int tt = 0; tt < NT; ++tt) {
        int s = tt & 1;
        const __bf16* Asl = (const __bf16*)(smem + s * 65536);
        const __bf16* Bsl = (const __bf16*)(smem + s * 65536 + 32768);
        #pragma unroll
        for (int ks = 0; ks < 2; ++ks) {
            int sa = ks * 4 + lk;
            bf16x8 af[8], bfr[4];
            #pragma unroll
            for (int i = 0; i < 8; ++i) {
                int ra = wmr * 128 + i * 16 + lr;
                af[i] = *(const bf16x8*)&Asl[ra * 64 + ((sa ^ (ra & 7)) << 3)];
            }
            #pragma unroll
            for (int j = 0; j < 4; ++j) {
                int rb = wnc * 64 + j * 16 + lr;
                bfr[j] = *(const bf16x8*)&Bsl[rb * 64 + ((sa ^ (rb & 7)) << 3)];
            }
            __builtin_amdgcn_s_setprio(1);
            #pragma unroll
            for (int i = 0; i < 8; ++i)
                #pragma unroll
                for (int j = 0; j < 4; ++j)
                    acc[i][j] = __builtin_amdgcn_mfma_f32_16x16x32_bf16(af[i], bfr[j], acc[i][j], 0, 0, 0);
            __builtin_amdgcn_s_setprio(0);
        }
        if (tt == NT - 1) break;
        S_BARRIER();                             // all waves done reading slot s
        if (tt + 2 < NT) {
            stage_tile<LDA>(Ab, Bb, smem, s, (tt + 2) * 64, rowin, sl8, wid);
            VMCNT8();                            // tile tt+1 done; tt+2 in flight
        } else {
            VMCNT0();                            // last prefetched tile
        }
        S_BARRIER();                             // tile tt+1 visible
    }

    if constexpr (MODE == 0) {
        #pragma unroll
        for (int j = 0; j < 4; ++j) {
            int e = (nblk << 8) + wnc * 64 + j * 16 + lr;
            float bias = bv[e];
            #pragma unroll
            for (int i = 0; i < 8; ++i) {
                int m0 = (mblk << 8) + wmr * 128 + i * 16 + (lk << 2);
                int b = m0 >> 11, s0 = m0 & 2047;
                bf16x4 o;
                #pragma unroll
                for (int r = 0; r < 4; ++r) o[r] = (__bf16)(acc[i][j][r] + bias);
                *(bf16x4*)&outVt[(((size_t)(b << 10) + e) << 11) + s0] = o;
            }
        }
    } else {
        float* ob = outF + (size_t)bb * S * Dd;
        #pragma unroll
        for (int i = 0; i < 8; ++i) {
            int m0 = (mblk << 8) + wmr * 128 + i * 16 + (lk << 2);
            #pragma unroll
            for (int j = 0; j < 4; ++j) {
                int e = (nblk << 8) + wnc * 64 + j * 16 + lr;
                #pragma unroll
                for (int r = 0; r < 4; ++r)
                    ob[(size_t)(m0 + r) * 1024 + e] = acc[i][j][r];
            }
        }
    }
}

// ---------------------------------------------------------------------------
extern "C" void kernel_launch(void* const* d_in, const int* in_sizes, int n_in,
                              void* d_out, int out_size, void* d_ws, size_t ws_size,
                              hipStream_t stream)
{
    const float* x  = (const float*)d_in[0];
    const float* Wq = (const float*)d_in[1];
    const float* bq = (const float*)d_in[2];
    const float* Wk = (const float*)d_in[3];
    const float* bk = (const float*)d_in[4];
    const float* Wv = (const float*)d_in[5];
    const float* bv = (const float*)d_in[6];

    float* outp  = (float*)d_out;
    float* attnF = outp + OUT0;

    if (ws_size < WS_NEED) return;
    char* ws = (char*)d_ws;
    __bf16* xbf   = (__bf16*)(ws + OFF_XBF);
    __bf16* wvt   = (__bf16*)(ws + OFF_WVT);
    __bf16* wqkT  = (__bf16*)(ws + OFF_WQKT);
    float*  qbuf  = (float*)(ws + OFF_Q);
    float*  kbuf  = (float*)(ws + OFF_K);
    __bf16* vt    = (__bf16*)(ws + OFF_VT);
    __bf16* attnB = (__bf16*)(ws + OFF_ATTB);

    prep_kernel<<<4368, 256, 0, stream>>>(x, Wq, Wk, Wv, xbf, wvt, wqkT);
    qk_proj_kernel<<<256, 256, 0, stream>>>(xbf, wqkT, bq, bk, qbuf, kbuf);
    gemm_kernel<0><<<256, 512, 0, stream>>>(xbf, wvt, nullptr, vt, bv);
    softmax_kernel<<<512, 256, 0, stream>>>(qbuf, kbuf, attnF, attnB);
    gemm_kernel<1><<<256, 512, 0, stream>>>(attnB, vt, outp, nullptr, nullptr);
}

// Round 3
// 196.293 us; speedup vs baseline: 1.2182x; 1.0087x over previous
//
#include <hip/hip_runtime.h>

// ---------------------------------------------------------------------------
// FactorizedSynthesizerRandom: B=8, S=2048, D=1024, K=8
//   q = x@Wq+bq, k = x@Wk+bk  (rank-8)
//   attn = softmax(q k^T)                        -> output[1] (f32, 8x2048x2048)
//   out  = attn @ (x@Wv+bv)                      -> output[0] (f32, 8x2048x1024)
// Round 3: full 8-phase (4 phases/K-tile, 2 K-tiles in flight) schedule:
//   per phase {ds_read subtile || stage chunk -> barrier -> lgkm0 -> setprio ->
//   16 MFMA -> setprio -> barrier}; counted vmcnt(8) at tile boundary only.
// ---------------------------------------------------------------------------

typedef __attribute__((ext_vector_type(8))) __bf16 bf16x8;
typedef __attribute__((ext_vector_type(4))) __bf16 bf16x4;
typedef __attribute__((ext_vector_type(4))) float  f32x4;
typedef unsigned int u32;

#define GLB_CAST(p) ((const __attribute__((address_space(1))) u32*)(p))
#define LDS_CAST(p) ((__attribute__((address_space(3))) u32*)(p))

#define S_BARRIER() { __builtin_amdgcn_s_barrier(); __builtin_amdgcn_sched_barrier(0); }
#define LGKM0()     { asm volatile("s_waitcnt lgkmcnt(0)" ::: "memory"); __builtin_amdgcn_sched_barrier(0); }
#define VMCNT8()    { asm volatile("s_waitcnt vmcnt(8)" ::: "memory"); __builtin_amdgcn_sched_barrier(0); }
#define VMCNT0()    { asm volatile("s_waitcnt vmcnt(0)" ::: "memory"); __builtin_amdgcn_sched_barrier(0); }

static constexpr int    Bn   = 8;
static constexpr int    S    = 2048;
static constexpr int    Dd   = 1024;
static constexpr int    Mtot = Bn * S;            // 16384
static constexpr size_t OUT0 = (size_t)Bn * S * Dd;   // out elements

// workspace layout (bytes)
static constexpr size_t OFF_XBF  = 0;                          // [16384][1024] bf16
static constexpr size_t OFF_WVT  = OFF_XBF  + (size_t)Mtot * Dd * 2;   // [1024][1024] bf16 (Wv^T)
static constexpr size_t OFF_WQKT = OFF_WVT  + (size_t)Dd * Dd * 2;     // [16][1024] bf16
static constexpr size_t OFF_Q    = OFF_WQKT + (size_t)16 * Dd * 2;     // [16384][8] f32
static constexpr size_t OFF_K    = OFF_Q    + (size_t)Mtot * 8 * 4;    // [16384][8] f32
static constexpr size_t OFF_VT   = OFF_K    + (size_t)Mtot * 8 * 4;    // [8][1024][2048] bf16 (value^T)
static constexpr size_t OFF_ATTB = OFF_VT   + (size_t)Bn * Dd * S * 2; // [8][2048][2048] bf16
static constexpr size_t WS_NEED  = OFF_ATTB + (size_t)Bn * S * S * 2;  // ~137 MB

// ---------------------------------------------------------------------------
// prep: blocks [0,4096): x f32 -> bf16 ; [4096,4352): Wv -> Wv^T bf16 ;
//       [4352,4368): [Wq|Wk]^T bf16  ([16][1024])
// ---------------------------------------------------------------------------
__global__ __launch_bounds__(256) void prep_kernel(
    const float* __restrict__ x, const float* __restrict__ Wq,
    const float* __restrict__ Wk, const float* __restrict__ Wv,
    __bf16* __restrict__ xbf, __bf16* __restrict__ wvt, __bf16* __restrict__ wqkT)
{
    __shared__ float lt[64][65];
    int bid = blockIdx.x, t = threadIdx.x;
    if (bid < 4096) {
        #pragma unroll
        for (int i = 0; i < 4; ++i) {
            size_t idx4 = (size_t)i * 1048576 + (size_t)bid * 256 + t;  // float4 index
            f32x4 v = ((const f32x4*)x)[idx4];
            bf16x4 o;
            #pragma unroll
            for (int c = 0; c < 4; ++c) o[c] = (__bf16)v[c];
            ((bf16x4*)xbf)[idx4] = o;
        }
    } else if (bid < 4352) {
        int tile = bid - 4096;             // 256 tiles of 64x64
        int tr = tile >> 4, tc = tile & 15;
        int r0 = t >> 6, c = t & 63;
        #pragma unroll
        for (int i = 0; i < 16; ++i) {
            int row = i * 4 + r0;
            lt[row][c] = Wv[(size_t)(tr * 64 + row) * 1024 + tc * 64 + c];
        }
        __syncthreads();
        #pragma unroll
        for (int i = 0; i < 16; ++i) {
            int er = i * 4 + r0;
            wvt[(size_t)(tc * 64 + er) * 1024 + tr * 64 + c] = (__bf16)lt[c][er];
        }
    } else {
        int lb = bid - 4352;               // 16 blocks cover 16*1024 elems
        #pragma unroll
        for (int i = 0; i < 4; ++i) {
            int idx = (lb * 4 + i) * 256 + t;   // 0..16383
            int n = idx >> 10, d = idx & 1023;
            float v = (n < 8) ? Wq[d * 8 + n] : Wk[d * 8 + (n & 7)];
            wqkT[n * 1024 + d] = (__bf16)v;
        }
    }
}

// ---------------------------------------------------------------------------
// q/k projection (rank-8, tiny): one wave per 16 rows, single 16x16 fragment.
// ---------------------------------------------------------------------------
__global__ __launch_bounds__(256) void qk_proj_kernel(
    const __bf16* __restrict__ xbf, const __bf16* __restrict__ wqkT,
    const float* __restrict__ bq, const float* __restrict__ bk,
    float* __restrict__ qb, float* __restrict__ kb)
{
    int t = threadIdx.x, l = t & 63, w = t >> 6;
    int mbase = (blockIdx.x * 4 + w) * 16;
    f32x4 acc = {0.f, 0.f, 0.f, 0.f};
    const __bf16* ar = xbf + (size_t)(mbase + (l & 15)) * 1024 + ((l >> 4) << 3);
    const __bf16* br = wqkT + (size_t)(l & 15) * 1024 + ((l >> 4) << 3);
    #pragma unroll 8
    for (int kk = 0; kk < 1024; kk += 32) {
        bf16x8 a = *(const bf16x8*)(ar + kk);
        bf16x8 b = *(const bf16x8*)(br + kk);
        acc = __builtin_amdgcn_mfma_f32_16x16x32_bf16(a, b, acc, 0, 0, 0);
    }
    int n = l & 15;
    float bias = (n < 8) ? bq[n] : bk[n & 7];
    #pragma unroll
    for (int r = 0; r < 4; ++r) {
        int m = mbase + ((l >> 4) << 2) + r;
        float v = acc[r] + bias;
        if (n < 8) qb[m * 8 + n] = v;
        else       kb[m * 8 + (n & 7)] = v;
    }
}

// ---------------------------------------------------------------------------
// softmax: thread t owns cols j = t*8..t*8+7, k-slice in registers.
// Writes attn f32 (d_out) and attn bf16 (ws, PV GEMM input).
// ---------------------------------------------------------------------------
__global__ __launch_bounds__(256) void softmax_kernel(
    const float* __restrict__ qb, const float* __restrict__ kb,
    float* __restrict__ attnF, __bf16* __restrict__ attnB)
{
    int bid = blockIdx.x;
    int b = bid >> 6, chunk = bid & 63;       // 64 chunks x 32 rows = 2048
    int t = threadIdx.x, l = t & 63, w = t >> 6;
    float kr[8][8];
    const float* kbb = kb + ((size_t)b << 14);
    #pragma unroll
    for (int jj = 0; jj < 8; ++jj) {
        f32x4 v0 = *(const f32x4*)(kbb + (size_t)(t * 8 + jj) * 8);
        f32x4 v1 = *(const f32x4*)(kbb + (size_t)(t * 8 + jj) * 8 + 4);
        #pragma unroll
        for (int c = 0; c < 4; ++c) { kr[jj][c] = v0[c]; kr[jj][4 + c] = v1[c]; }
    }
    __shared__ float redm[4], reds[4];
    const float* qrow = qb + ((size_t)b << 14);
    for (int ii = 0; ii < 32; ++ii) {
        int i = (chunk << 5) + ii;
        f32x4 q0 = *(const f32x4*)(qrow + (size_t)i * 8);
        f32x4 q1 = *(const f32x4*)(qrow + (size_t)i * 8 + 4);
        float e[8];
        #pragma unroll
        for (int jj = 0; jj < 8; ++jj) {
            float s = q0[0] * kr[jj][0];
            s = fmaf(q0[1], kr[jj][1], s);
            s = fmaf(q0[2], kr[jj][2], s);
            s = fmaf(q0[3], kr[jj][3], s);
            s = fmaf(q1[0], kr[jj][4], s);
            s = fmaf(q1[1], kr[jj][5], s);
            s = fmaf(q1[2], kr[jj][6], s);
            s = fmaf(q1[3], kr[jj][7], s);
            e[jj] = s;
        }
        float mx = e[0];
        #pragma unroll
        for (int jj = 1; jj < 8; ++jj) mx = fmaxf(mx, e[jj]);
        #pragma unroll
        for (int d = 1; d < 64; d <<= 1) mx = fmaxf(mx, __shfl_xor(mx, d));
        if (l == 0) redm[w] = mx;
        __syncthreads();
        mx = fmaxf(fmaxf(redm[0], redm[1]), fmaxf(redm[2], redm[3]));
        float p[8], sum = 0.f;
        #pragma unroll
        for (int jj = 0; jj < 8; ++jj) { p[jj] = __expf(e[jj] - mx); sum += p[jj]; }
        #pragma unroll
        for (int d = 1; d < 64; d <<= 1) sum += __shfl_xor(sum, d);
        if (l == 0) reds[w] = sum;
        __syncthreads();
        float T = (reds[0] + reds[1]) + (reds[2] + reds[3]);
        float inv = 1.0f / T;
        size_t off = (((size_t)b << 11) + i) * 2048 + (size_t)t * 8;
        f32x4 o0, o1; bf16x8 ob;
        #pragma unroll
        for (int c = 0; c < 4; ++c) {
            o0[c] = p[c] * inv; o1[c] = p[4 + c] * inv;
            ob[c] = (__bf16)o0[c]; ob[4 + c] = (__bf16)o1[c];
        }
        *(f32x4*)(attnF + off) = o0;
        *(f32x4*)(attnF + off + 4) = o1;
        *(bf16x8*)(attnB + off) = ob;
    }
}

// ---------------------------------------------------------------------------
// 8-phase GEMM: C[256x256] = A[M][Kz] * Bt[N][Kz]^T (bf16 row-major, row
// stride = Kz). 512 threads = 8 waves (2M x 4N), per-wave 128x64 output.
// LDS: 2 slots x (A 32KB + B 32KB), 16B-slot XOR swizzle (slot ^= row&7) via
// pre-swizzled global source. Per K-tile: 4 quadrant phases; stage chunks for
// tile t+2 are issued only after the barrier proving their LDS target chunk
// was consumed (A0/A2 after P0, B0-3 after P1, A1/A3 after P2); vmcnt(8) at
// the tile boundary only (tile t+1 landed, t+2 still in flight).
// MODE 0: out = value^T bf16 [b][e][s] + bias bv[e]  (A=xbf, Bt=WvT, K=1024)
// MODE 1: out = f32 [b][i][e]                        (A=attnB, Bt=vt, K=2048)
// ---------------------------------------------------------------------------
template<int LDA>
__device__ __forceinline__ void stageA(const __bf16* Ab, char* smem,
    int slot, int kk, int c, int rowin, int sl8, int wid)
{
    __builtin_amdgcn_global_load_lds(
        GLB_CAST(Ab + (size_t)(c * 64 + rowin) * LDA + kk + sl8 * 8),
        LDS_CAST(smem + slot * 65536 + c * 8192 + wid * 1024), 16, 0, 0);
}
template<int LDA>
__device__ __forceinline__ void stageB(const __bf16* Bb, char* smem,
    int slot, int kk, int c, int rowin, int sl8, int wid)
{
    __builtin_amdgcn_global_load_lds(
        GLB_CAST(Bb + (size_t)(c * 64 + rowin) * LDA + kk + sl8 * 8),
        LDS_CAST(smem + slot * 65536 + 32768 + c * 8192 + wid * 1024), 16, 0, 0);
}

template<int MODE>
__global__ __launch_bounds__(512, 2) void gemm_kernel(
    const __bf16* __restrict__ A, const __bf16* __restrict__ Bt,
    float* __restrict__ outF, __bf16* __restrict__ outVt,
    const float* __restrict__ bv)
{
    constexpr int LDA = (MODE == 0) ? 1024 : 2048;
    constexpr int NT  = LDA / 64;               // K-tiles (K == LDA in both uses)
    __shared__ __align__(1024) char smem[131072];

    int bid = blockIdx.x;
    int wg = ((bid & 7) << 5) | (bid >> 3);     // bijective XCD swizzle (nwg=256)
    int t = threadIdx.x, l = t & 63;
    int wid = t >> 6;
    int wmr = wid >> 2, wnc = wid & 3;          // wave grid 2(M) x 4(N)

    int mblk, nblk, bb = 0;
    size_t aoff, boff;
    if constexpr (MODE == 0) {
        mblk = wg >> 2; nblk = wg & 3;          // 64 x 4
        aoff = (size_t)mblk * 256 * LDA; boff = 0;
    } else {
        bb = wg >> 5; int r = wg & 31;          // one batch per XCD
        mblk = r >> 2; nblk = r & 3;            // 8 x 4
        aoff = (size_t)bb * S * S + (size_t)mblk * 256 * LDA;
        boff = (size_t)bb * Dd * S;
    }
    const __bf16* Ab = A + aoff;
    const __bf16* Bb = Bt + boff + (size_t)nblk * 256 * LDA;

    int rowin = t >> 3;                         // 0..63
    int sl8 = (t & 7) ^ (rowin & 7);            // pre-swizzled global 16B-slot
    int lr = l & 15, lk = l >> 4;

    f32x4 acc[8][4] = {};

    // prologue: tiles 0,1 fully staged; wait tile0 (tile1 stays in flight).
    #pragma unroll
    for (int c = 0; c < 4; ++c) {
        stageA<LDA>(Ab, smem, 0, 0, c, rowin, sl8, wid);
        stageB<LDA>(Bb, smem, 0, 0, c, rowin, sl8, wid);
    }
    #pragma unroll
    for (int c = 0; c < 4; ++c) {
        stageA<LDA>(Ab, smem, 1, 64, c, rowin, sl8, wid);
        stageB<LDA>(Bb, smem, 1, 64, c, rowin, sl8, wid);
    }
    VMCNT8();
    S_BARRIER();

    for (int tt = 0; tt < NT; ++tt) {
        int s = tt & 1;
        const __bf16* Asl = (const __bf16*)(smem + s * 65536);
        const __bf16* Bsl = (const __bf16*)(smem + s * 65536 + 32768);
        bool pf = (tt + 2 < NT);
        int kk2 = (tt + 2) * 64;

        bf16x8 aLo[2][4], aHi[2][4], bLo[2][2], bHi[2][2];

        // ---- P0: read A-lo + B-lo; MFMA Q00 (i0-3, j0-1)
        #pragma unroll
        for (int ks = 0; ks < 2; ++ks) {
            int sa = ks * 4 + lk;
            #pragma unroll
            for (int i = 0; i < 4; ++i) {
                int ra = wmr * 128 + i * 16 + lr;
                aLo[ks][i] = *(const bf16x8*)&Asl[ra * 64 + ((sa ^ (ra & 7)) << 3)];
            }
            #pragma unroll
            for (int j = 0; j < 2; ++j) {
                int rb = wnc * 64 + j * 16 + lr;
                bLo[ks][j] = *(const bf16x8*)&Bsl[rb * 64 + ((sa ^ (rb & 7)) << 3)];
            }
        }
        S_BARRIER(); LGKM0();
        __builtin_amdgcn_s_setprio(1);
        #pragma unroll
        for (int ks = 0; ks < 2; ++ks)
            #pragma unroll
            for (int i = 0; i < 4; ++i)
                #pragma unroll
                for (int j = 0; j < 2; ++j)
                    acc[i][j] = __builtin_amdgcn_mfma_f32_16x16x32_bf16(aLo[ks][i], bLo[ks][j], acc[i][j], 0, 0, 0);
        __builtin_amdgcn_s_setprio(0);
        S_BARRIER();                             // A-chunks 0,2 consumed

        // ---- P1: read B-hi; stage A0,A2(t+2); MFMA Q01 (i0-3, j2-3)
        #pragma unroll
        for (int ks = 0; ks < 2; ++ks) {
            int sa = ks * 4 + lk;
            #pragma unroll
            for (int j = 0; j < 2; ++j) {
                int rb = wnc * 64 + (j + 2) * 16 + lr;
                bHi[ks][j] = *(const bf16x8*)&Bsl[rb * 64 + ((sa ^ (rb & 7)) << 3)];
            }
        }
        if (pf) {
            stageA<LDA>(Ab, smem, s, kk2, 0, rowin, sl8, wid);
            stageA<LDA>(Ab, smem, s, kk2, 2, rowin, sl8, wid);
        }
        S_BARRIER(); LGKM0();
        __builtin_amdgcn_s_setprio(1);
        #pragma unroll
        for (int ks = 0; ks < 2; ++ks)
            #pragma unroll
            for (int i = 0; i < 4; ++i)
                #pragma unroll
                for (int j = 0; j < 2; ++j)
                    acc[i][2 + j] = __builtin_amdgcn_mfma_f32_16x16x32_bf16(aLo[ks][i], bHi[ks][j], acc[i][2 + j], 0, 0, 0);
        __builtin_amdgcn_s_setprio(0);
        S_BARRIER();                             // all B-chunks consumed

        // ---- P2: read A-hi; stage B0-3(t+2); MFMA Q11 (i4-7, j2-3)
        #pragma unroll
        for (int ks = 0; ks < 2; ++ks) {
            int sa = ks * 4 + lk;
            #pragma unroll
            for (int i = 0; i < 4; ++i) {
                int ra = wmr * 128 + (i + 4) * 16 + lr;
                aHi[ks][i] = *(const bf16x8*)&Asl[ra * 64 + ((sa ^ (ra & 7)) << 3)];
            }
        }
        if (pf) {
            #pragma unroll
            for (int c = 0; c < 4; ++c)
                stageB<LDA>(Bb, smem, s, kk2, c, rowin, sl8, wid);
        }
        S_BARRIER(); LGKM0();
        __builtin_amdgcn_s_setprio(1);
        #pragma unroll
        for (int ks = 0; ks < 2; ++ks)
            #pragma unroll
            for (int i = 0; i < 4; ++i)
                #pragma unroll
                for (int j = 0; j < 2; ++j)
                    acc[4 + i][2 + j] = __builtin_amdgcn_mfma_f32_16x16x32_bf16(aHi[ks][i], bHi[ks][j], acc[4 + i][2 + j], 0, 0, 0);
        __builtin_amdgcn_s_setprio(0);
        S_BARRIER();                             // A-chunks 1,3 consumed

        // ---- P3: stage A1,A3(t+2); MFMA Q10 (i4-7, j0-1)
        if (pf) {
            stageA<LDA>(Ab, smem, s, kk2, 1, rowin, sl8, wid);
            stageA<LDA>(Ab, smem, s, kk2, 3, rowin, sl8, wid);
        }
        S_BARRIER();
        __builtin_amdgcn_s_setprio(1);
        #pragma unroll
        for (int ks = 0; ks < 2; ++ks)
            #pragma unroll
            for (int i = 0; i < 4; ++i)
                #pragma unroll
                for (int j = 0; j < 2; ++j)
                    acc[4 + i][j] = __builtin_amdgcn_mfma_f32_16x16x32_bf16(aHi[ks][i], bLo[ks][j], acc[4 + i][j], 0, 0, 0);
        __builtin_amdgcn_s_setprio(0);

        if (tt == NT - 1) break;
        S_BARRIER();
        if (pf) { VMCNT8(); } else { VMCNT0(); }  // tile t+1 landed
        S_BARRIER();
    }

    if constexpr (MODE == 0) {
        #pragma unroll
        for (int j = 0; j < 4; ++j) {
            int e = (nblk << 8) + wnc * 64 + j * 16 + lr;
            float bias = bv[e];
            #pragma unroll
            for (int i = 0; i < 8; ++i) {
                int m0 = (mblk << 8) + wmr * 128 + i * 16 + (lk << 2);
                int b = m0 >> 11, s0 = m0 & 2047;
                bf16x4 o;
                #pragma unroll
                for (int r = 0; r < 4; ++r) o[r] = (__bf16)(acc[i][j][r] + bias);
                *(bf16x4*)&outVt[(((size_t)(b << 10) + e) << 11) + s0] = o;
            }
        }
    } else {
        float* ob = outF + (size_t)bb * S * Dd;
        #pragma unroll
        for (int i = 0; i < 8; ++i) {
            int m0 = (mblk << 8) + wmr * 128 + i * 16 + (lk << 2);
            #pragma unroll
            for (int j = 0; j < 4; ++j) {
                int e = (nblk << 8) + wnc * 64 + j * 16 + lr;
                #pragma unroll
                for (int r = 0; r < 4; ++r)
                    ob[(size_t)(m0 + r) * 1024 + e] = acc[i][j][r];
            }
        }
    }
}

// ---------------------------------------------------------------------------
extern "C" void kernel_launch(void* const* d_in, const int* in_sizes, int n_in,
                              void* d_out, int out_size, void* d_ws, size_t ws_size,
                              hipStream_t stream)
{
    const float* x  = (const float*)d_in[0];
    const float* Wq = (const float*)d_in[1];
    const float* bq = (const float*)d_in[2];
    const float* Wk = (const float*)d_in[3];
    const float* bk = (const float*)d_in[4];
    const float* Wv = (const float*)d_in[5];
    const float* bv = (const float*)d_in[6];

    float* outp  = (float*)d_out;
    float* attnF = outp + OUT0;

    if (ws_size < WS_NEED) return;
    char* ws = (char*)d_ws;
    __bf16* xbf   = (__bf16*)(ws + OFF_XBF);
    __bf16* wvt   = (__bf16*)(ws + OFF_WVT);
    __bf16* wqkT  = (__bf16*)(ws + OFF_WQKT);
    float*  qbuf  = (float*)(ws + OFF_Q);
    float*  kbuf  = (float*)(ws + OFF_K);
    __bf16* vt    = (__bf16*)(ws + OFF_VT);
    __bf16* attnB = (__bf16*)(ws + OFF_ATTB);

    prep_kernel<<<4368, 256, 0, stream>>>(x, Wq, Wk, Wv, xbf, wvt, wqkT);
    qk_proj_kernel<<<256, 256, 0, stream>>>(xbf, wqkT, bq, bk, qbuf, kbuf);
    gemm_kernel<0><<<256, 512, 0, stream>>>(xbf, wvt, nullptr, vt, bv);
    softmax_kernel<<<512, 256, 0, stream>>>(qbuf, kbuf, attnF, attnB);
    gemm_kernel<1><<<256, 512, 0, stream>>>(attnB, vt, outp, nullptr, nullptr);
}